// Round 1
// baseline (30.330 us; speedup 1.0000x reference)
//
#include <hip/hip_runtime.h>

// out[b,o] = (rowsum(x)[b] + rowsum(w)[o]) * bias[o]
// B=8192, IN=2048, OUT=2048, all float32.

#define B_DIM 8192
#define IN_DIM 2048
#define OUT_DIM 2048

// One 256-thread block per row; rows [0,8192) from x, [8192,10240) from weight.
// Each thread: 8 floats (2x float4). Wave shuffle reduce, LDS combine of 4 waves.
__global__ __launch_bounds__(256) void rowsum_kernel(const float* __restrict__ x,
                                                     const float* __restrict__ w,
                                                     const float* __restrict__ bias,
                                                     float* __restrict__ xsum,   // [B_DIM]
                                                     float* __restrict__ wsb) {  // [OUT_DIM], = w_sum*bias
    const int row = blockIdx.x;          // 0 .. B_DIM+OUT_DIM-1
    const int tid = threadIdx.x;         // 0 .. 255
    const bool is_w = row >= B_DIM;
    const float* src = is_w ? (w + (size_t)(row - B_DIM) * IN_DIM)
                            : (x + (size_t)row * IN_DIM);
    const float4* src4 = reinterpret_cast<const float4*>(src);
    float4 a = src4[tid];          // floats [0,1024)
    float4 b = src4[tid + 256];    // floats [1024,2048)
    float s = (a.x + a.y) + (a.z + a.w) + (b.x + b.y) + (b.z + b.w);

    // 64-lane wave reduction
    #pragma unroll
    for (int off = 32; off > 0; off >>= 1)
        s += __shfl_down(s, off, 64);

    __shared__ float ls[4];
    if ((tid & 63) == 0) ls[tid >> 6] = s;
    __syncthreads();
    if (tid == 0) {
        float tot = (ls[0] + ls[1]) + (ls[2] + ls[3]);
        if (is_w) {
            int o = row - B_DIM;
            wsb[o] = tot * bias[o];
        } else {
            xsum[row] = tot;
        }
    }
}

// Grid-stride over output in float4 units. out4[idx] = xsum[b]*bias4[oc] + wsb4[oc]
__global__ __launch_bounds__(256) void write_kernel(const float* __restrict__ xsum,
                                                    const float* __restrict__ wsb,
                                                    const float* __restrict__ bias,
                                                    float4* __restrict__ out4) {
    const float4* bias4 = reinterpret_cast<const float4*>(bias);
    const float4* wsb4  = reinterpret_cast<const float4*>(wsb);
    const int total4 = B_DIM * (OUT_DIM / 4);           // 4,194,304
    int idx = blockIdx.x * blockDim.x + threadIdx.x;
    const int stride = gridDim.x * blockDim.x;
    for (; idx < total4; idx += stride) {
        const int b  = idx >> 9;        // / (OUT_DIM/4) = /512
        const int oc = idx & 511;       // % 512
        const float  xs = xsum[b];
        const float4 bi = bias4[oc];
        const float4 ws = wsb4[oc];
        float4 o;
        o.x = fmaf(xs, bi.x, ws.x);
        o.y = fmaf(xs, bi.y, ws.y);
        o.z = fmaf(xs, bi.z, ws.z);
        o.w = fmaf(xs, bi.w, ws.w);
        out4[idx] = o;
    }
}

extern "C" void kernel_launch(void* const* d_in, const int* in_sizes, int n_in,
                              void* d_out, int out_size, void* d_ws, size_t ws_size,
                              hipStream_t stream) {
    const float* x    = (const float*)d_in[0];   // [8192, 2048]
    const float* w    = (const float*)d_in[1];   // [2048, 2048]
    const float* bias = (const float*)d_in[2];   // [2048]
    float* out  = (float*)d_out;                 // [8192, 2048]
    float* xsum = (float*)d_ws;                  // 8192 floats
    float* wsb  = xsum + B_DIM;                  // 2048 floats

    rowsum_kernel<<<B_DIM + OUT_DIM, 256, 0, stream>>>(x, w, bias, xsum, wsb);
    write_kernel<<<2048, 256, 0, stream>>>(xsum, wsb, bias, (float4*)out);
}

// Round 2
// 29.685 us; speedup vs baseline: 1.0217x; 1.0217x over previous
//
#include <hip/hip_runtime.h>

// out[b,o] = (rowsum(x)[b] + rowsum(w)[o]) * bias[o]
// B=8192, IN=2048, OUT=2048, all float32.
//
// Schedule: kernel A (tiny): wsb[o] = rowsum(w)[o] * bias[o]   (16 MiB read)
//           kernel B (big, fused): per x-row: reduce row -> xs, then
//                                  out[b,:] = xs*bias + wsb    (64 MiB R + 64 MiB W)

#define B_DIM 8192
#define IN_DIM 2048
#define OUT_DIM 2048

__device__ __forceinline__ float sum8(float4 a, float4 b) {
    return ((a.x + a.y) + (a.z + a.w)) + ((b.x + b.y) + (b.z + b.w));
}

__device__ __forceinline__ float wave_reduce(float s) {
    #pragma unroll
    for (int off = 32; off > 0; off >>= 1)
        s += __shfl_down(s, off, 64);
    return s;
}

// One 256-thread block per weight row.
__global__ __launch_bounds__(256) void wsb_kernel(const float* __restrict__ w,
                                                  const float* __restrict__ bias,
                                                  float* __restrict__ wsb) {
    const int row = blockIdx.x;          // 0 .. OUT_DIM-1
    const int tid = threadIdx.x;
    const float4* src4 = reinterpret_cast<const float4*>(w + (size_t)row * IN_DIM);
    float4 a = src4[tid];
    float4 b = src4[tid + 256];
    float s = wave_reduce(sum8(a, b));

    __shared__ float ls[4];
    if ((tid & 63) == 0) ls[tid >> 6] = s;
    __syncthreads();
    if (tid == 0)
        wsb[row] = ((ls[0] + ls[1]) + (ls[2] + ls[3])) * bias[row];
}

// One 256-thread block per x row: read row, reduce, write out row.
__global__ __launch_bounds__(256) void fused_row_kernel(const float* __restrict__ x,
                                                        const float* __restrict__ bias,
                                                        const float* __restrict__ wsb,
                                                        float4* __restrict__ out4) {
    const int row = blockIdx.x;          // 0 .. B_DIM-1
    const int tid = threadIdx.x;
    const float4* src4 = reinterpret_cast<const float4*>(x + (size_t)row * IN_DIM);
    const float4* bias4 = reinterpret_cast<const float4*>(bias);
    const float4* wsb4  = reinterpret_cast<const float4*>(wsb);

    // Issue all loads up front; bias/wsb are L2-resident and overlap the reduce.
    float4 a   = src4[tid];
    float4 b   = src4[tid + 256];
    float4 bi0 = bias4[tid];
    float4 bi1 = bias4[tid + 256];
    float4 ws0 = wsb4[tid];
    float4 ws1 = wsb4[tid + 256];

    float s = wave_reduce(sum8(a, b));

    __shared__ float ls[4];
    if ((tid & 63) == 0) ls[tid >> 6] = s;
    __syncthreads();
    const float xs = (ls[0] + ls[1]) + (ls[2] + ls[3]);   // broadcast read

    float4 o0, o1;
    o0.x = fmaf(xs, bi0.x, ws0.x);
    o0.y = fmaf(xs, bi0.y, ws0.y);
    o0.z = fmaf(xs, bi0.z, ws0.z);
    o0.w = fmaf(xs, bi0.w, ws0.w);
    o1.x = fmaf(xs, bi1.x, ws1.x);
    o1.y = fmaf(xs, bi1.y, ws1.y);
    o1.z = fmaf(xs, bi1.z, ws1.z);
    o1.w = fmaf(xs, bi1.w, ws1.w);

    const size_t base = (size_t)row * (OUT_DIM / 4);
    out4[base + tid]       = o0;
    out4[base + tid + 256] = o1;
}

extern "C" void kernel_launch(void* const* d_in, const int* in_sizes, int n_in,
                              void* d_out, int out_size, void* d_ws, size_t ws_size,
                              hipStream_t stream) {
    const float* x    = (const float*)d_in[0];   // [8192, 2048]
    const float* w    = (const float*)d_in[1];   // [2048, 2048]
    const float* bias = (const float*)d_in[2];   // [2048]
    float* out = (float*)d_out;                  // [8192, 2048]
    float* wsb = (float*)d_ws;                   // 2048 floats

    wsb_kernel<<<OUT_DIM, 256, 0, stream>>>(w, bias, wsb);
    fused_row_kernel<<<B_DIM, 256, 0, stream>>>(x, bias, wsb, (float4*)out);
}